// Round 5
// baseline (358.624 us; speedup 1.0000x reference)
//
#include <hip/hip_runtime.h>

#define WW   320
#define HH   160
#define CIN  80
#define COUT 32
#define DD   48
#define NB   8
#define VP   84                 // vol row pad (f32 words)
#define HWPX (HH * WW)          // 51200
#define NPX  (NB * HWPX)        // 409600 pixels per image

typedef __bf16 bf16x8 __attribute__((ext_vector_type(8)));
typedef float  float4v __attribute__((ext_vector_type(4)));

// ---------------- K0: fold BN into weights/bias (one tiny block) ----------
// Wp[c][o] = convw[o][c] * sc_c ;  biasp[o] = convb[o] + sum_c sh_c*convw[o][c]
__global__ void k0_fold(const float* __restrict__ gamma, const float* __restrict__ beta,
                        const float* __restrict__ bnmean, const float* __restrict__ bnvar,
                        const float* __restrict__ convw, const float* __restrict__ convb,
                        float* __restrict__ Wp, float* __restrict__ biasp)
{
    const int t = threadIdx.x;
    for (int idx = t; idx < CIN * COUT; idx += 256) {
        int c = idx >> 5, o = idx & 31;
        float sc = gamma[c] * rsqrtf(bnvar[c] + 1e-5f);
        Wp[idx] = convw[o * CIN + c] * sc;
    }
    if (t < COUT) {
        float s = convb[t];
        for (int c = 0; c < CIN; ++c) {
            float sc = gamma[c] * rsqrtf(bnvar[c] + 1e-5f);
            float sh = fmaf(-bnmean[c], sc, beta[c]);
            s = fmaf(sh, convw[t * CIN + c], s);
        }
        biasp[t] = s;
    }
}

// ---------------- K1: streaming preconv, no LDS, no barriers --------------
// 1 thread = 1 pixel of one image. acc[32] fp32, 8-deep load batches.
// Output feat bf16 [pixel][32], 16B groups g stored at slot g^((w>>1)&3)
// (pre-swizzled so K2's LDS image is conflict-free for MFMA frag reads).
__global__ __launch_bounds__(256, 6)
void k1_preconv(const float* __restrict__ inL, const float* __restrict__ inR,
                const float* __restrict__ Wp, const float* __restrict__ biasp,
                __bf16* __restrict__ featL, __bf16* __restrict__ featR)
{
    const int pid = blockIdx.x * 256 + threadIdx.x;   // 0..819199
    const int img = (pid >= NPX) ? 1 : 0;
    const int p   = pid - img * NPX;                  // pixel within image
    const float* __restrict__ src = img ? inR : inL;
    __bf16* __restrict__ dst = img ? featR : featL;

    const int b  = p / HWPX;
    const int hw = p - b * HWPX;
    const float* px = src + (size_t)b * CIN * HWPX + hw;

    float acc[COUT];
    #pragma unroll
    for (int o = 0; o < COUT; ++o) acc[o] = biasp[o];      // uniform s_load

    for (int cb = 0; cb < CIN; cb += 8) {
        float x[8];
        #pragma unroll
        for (int u = 0; u < 8; ++u)                        // 8 loads in flight
            x[u] = px[(size_t)(cb + u) * HWPX];
        #pragma unroll
        for (int u = 0; u < 8; ++u) {
            float tv = fmaxf(x[u], 0.f);
            const float* wrow = Wp + (cb + u) * COUT;      // uniform s_loads
            #pragma unroll
            for (int o = 0; o < COUT; ++o)
                acc[o] = fmaf(tv, wrow[o], acc[o]);
        }
    }

    const int w  = hw % WW;
    const int sw = (w >> 1) & 3;
    #pragma unroll
    for (int g = 0; g < 4; ++g) {
        bf16x8 pk;
        #pragma unroll
        for (int j = 0; j < 8; ++j) pk[j] = (__bf16)acc[g * 8 + j];
        *(bf16x8*)(dst + (size_t)p * COUT + ((g ^ sw) << 3) ) = pk;
    }
}

// ---------------- K2: banded volume via MFMA (R4's proven P2) -------------
__global__ __launch_bounds__(320, 2)
void k2_volume(const __bf16* __restrict__ featL, const __bf16* __restrict__ featR,
               float* __restrict__ out)
{
    __shared__ __align__(16) __bf16 fLs[WW * COUT];   // 20480 B
    __shared__ __align__(16) __bf16 fRs[WW * COUT];   // 20480 B
    __shared__ __align__(16) float  vol[DD * VP];     // 16128 B

    const int t = threadIdx.x;                        // 0..319
    const int b = blockIdx.x / HH;
    const int h = blockIdx.x % HH;
    const int wave = t >> 6, lane = t & 63, ln15 = lane & 15, quad = lane >> 4;

    // ---- stage both feat rows (pre-swizzled layout, identity copy) ----
    const size_t rowOff = ((size_t)b * HH + h) * WW * COUT;
    const __bf16* gL = featL + rowOff;
    const __bf16* gR = featR + rowOff;
    {
        bf16x8 tl[4], tr[4];
        #pragma unroll
        for (int it = 0; it < 4; ++it) {              // 8 loads in flight
            int e = it * 2560 + t * 8;
            tl[it] = *(const bf16x8*)(gL + e);
            tr[it] = *(const bf16x8*)(gR + e);
        }
        #pragma unroll
        for (int it = 0; it < 4; ++it) {
            int e = it * 2560 + t * 8;
            *(bf16x8*)(fLs + e) = tl[it];
            *(bf16x8*)(fRs + e) = tr[it];
        }
    }
    __syncthreads();

    // ---- banded A^T*B, 4 passes of 80 w-columns ----
    for (int pass = 0; pass < 4; ++pass) {
        for (int k = wave; k < 20; k += 5) {
            const int two = k >> 2;            // w-tile within pass: 0..4
            const int d   = k & 3;             // j-tile lag: 0..3
            const int tw  = pass * 5 + two;
            const int tj  = tw - d;
            if (tj >= 0) {
                const int wr = tw * 16 + ln15;  // A row (w)
                const int jr = tj * 16 + ln15;  // B row (j)
                bf16x8 av = *(const bf16x8*)(fLs + wr * COUT +
                                             ((quad ^ ((wr >> 1) & 3)) << 3));
                bf16x8 bv = *(const bf16x8*)(fRs + jr * COUT +
                                             ((quad ^ ((jr >> 1) & 3)) << 3));
                float4v cz = {0.f, 0.f, 0.f, 0.f};
                float4v dv = __builtin_amdgcn_mfma_f32_16x16x32_bf16(av, bv, cz, 0, 0, 0);
                #pragma unroll
                for (int r = 0; r < 4; ++r) {
                    int row = quad * 4 + r;
                    int i = 16 * d + row - ln15;   // disparity
                    if (i >= 0 && i < DD)
                        vol[i * VP + two * 16 + row] = dv[r] * (1.f / 32.f);
                }
            }
        }
        __syncthreads();

        // coalesced float4 store of 48 x 80 chunk; w<i band forced to 0
        for (int s = t; s < DD * 20; s += 320) {
            int i = s / 20, q = s - i * 20;
            int wg0 = pass * 80 + q * 4;
            float4v v = *(const float4v*)(vol + i * VP + q * 4);
            #pragma unroll
            for (int e = 0; e < 4; ++e)
                if (wg0 + e < i) v[e] = 0.f;
            *(float4v*)(out + ((size_t)(b * DD + i) * HH + h) * WW + wg0) = v;
        }
        __syncthreads();
    }
}

extern "C" void kernel_launch(void* const* d_in, const int* in_sizes, int n_in,
                              void* d_out, int out_size, void* d_ws, size_t ws_size,
                              hipStream_t stream) {
    const float* inL    = (const float*)d_in[0];
    const float* inR    = (const float*)d_in[1];
    const float* gamma  = (const float*)d_in[2];
    const float* beta   = (const float*)d_in[3];
    const float* bnmean = (const float*)d_in[4];
    const float* bnvar  = (const float*)d_in[5];
    const float* convw  = (const float*)d_in[6];
    const float* convb  = (const float*)d_in[7];
    float* out = (float*)d_out;

    // ws layout: Wp[2560] f32 | biasp[32] f32 | featL | featR (bf16, 26.2 MB each)
    char* ws = (char*)d_ws;
    float*  Wp    = (float*)ws;                         // 10240 B
    float*  biasp = (float*)(ws + 10240);               //   128 B
    __bf16* featL = (__bf16*)(ws + 16384);
    __bf16* featR = (__bf16*)(ws + 16384 + (size_t)NPX * COUT * 2);

    k0_fold<<<1, 256, 0, stream>>>(gamma, beta, bnmean, bnvar, convw, convb, Wp, biasp);
    k1_preconv<<<(2 * NPX) / 256, 256, 0, stream>>>(inL, inR, Wp, biasp, featL, featR);
    k2_volume<<<NB * HH, 320, 0, stream>>>(featL, featR, out);
}